// Round 1
// 576.615 us; speedup vs baseline: 1.1338x; 1.1338x over previous
//
#include <hip/hip_runtime.h>
#include <hip/hip_bf16.h>

typedef __hip_bfloat16 bf16;
typedef __attribute__((ext_vector_type(8))) short short8;   // 8 bf16 (4 VGPRs)
typedef __attribute__((ext_vector_type(4))) float f32x4;    // MFMA C/D

// async global->LDS, 16B per lane; LDS dest = wave-uniform base + lane*16
__device__ __forceinline__ void gload_lds16(const void* g, void* l) {
    __builtin_amdgcn_global_load_lds(
        (const __attribute__((address_space(1))) void*)g,
        (__attribute__((address_space(3))) void*)l, 16, 0, 0);
}

__device__ __forceinline__ void store_out(bf16* p, float v)  { *p = __float2bfloat16(v); }
__device__ __forceinline__ void store_out(float* p, float v) { *p = v; }

// ---------------------------------------------------------------------------
// fp32 -> bf16 conversion, 8 elems/thread. n must be a multiple of 2048.
// ---------------------------------------------------------------------------
__global__ __launch_bounds__(256)
void cvt_f32_bf16(const float* __restrict__ in, bf16* __restrict__ out, long n)
{
    const long i = ((long)blockIdx.x * 256 + threadIdx.x) * 8;
    if (i + 8 > n) return;
    float4 a = *(const float4*)(in + i);
    float4 b = *(const float4*)(in + i + 4);
    bf16 o[8];
    o[0] = __float2bfloat16(a.x); o[1] = __float2bfloat16(a.y);
    o[2] = __float2bfloat16(a.z); o[3] = __float2bfloat16(a.w);
    o[4] = __float2bfloat16(b.x); o[5] = __float2bfloat16(b.y);
    o[6] = __float2bfloat16(b.z); o[7] = __float2bfloat16(b.w);
    *(uint4*)(out + i) = *(const uint4*)o;
}

// ---------------------------------------------------------------------------
// C(M,N) = A(M,K) * Bt(N,K)^T + bias(N); A,Bt bf16, bias fp32, fp32 accum.
// 256x256 tile, BK=32, 512 threads = 8 waves in 2x4, each wave 128x64 (8x4 MFMA).
// 4-buffer LDS pipeline (128 KB), staging 3 K-tiles ahead via global_load_lds.
// One raw s_barrier + one counted s_waitcnt vmcnt(8) per K-tile; NO drains.
//   invariant: 4 gload issues per thread per K-tile (dummy re-stage of tile 0
//   into dead buffers at the tail keeps counts uniform). At the wait before
//   tile kt, outstanding <= 12; vmcnt(8) completes the 4 oldest = tile kt.
// Layout [256][32] row-major: gload dest linear, ds_read_b128 frag reads
// cover 1024 contiguous bytes per wave -> bank-conflict-free, no swizzle.
// ---------------------------------------------------------------------------
template <typename OutT>
__global__ __launch_bounds__(512, 2)
void gemm256(const bf16* __restrict__ A, const bf16* __restrict__ Bt,
             const float* __restrict__ bias, OutT* __restrict__ C,
             int N, int K, int gxt)
{
    __shared__ bf16 As[4][8192];   // 4 buffers x [256][32]
    __shared__ bf16 Bs[4][8192];

    // bijective XCD-aware block swizzle (m204 variant; works for any nwg)
    const int nwg  = gridDim.x;
    const int orig = blockIdx.x;
    const int qq = nwg >> 3, rr = nwg & 7, xc = orig & 7;
    const int wg = (xc < rr ? xc * (qq + 1) : rr * (qq + 1) + (xc - rr) * qq)
                 + (orig >> 3);
    const long m0 = (long)(wg / gxt) * 256;
    const long n0 = (long)(wg % gxt) * 256;

    const int tid = threadIdx.x;
    const int wv  = tid >> 6;            // wave 0..7
    const int ln  = tid & 63;
    const int l15 = ln & 15;
    const int qd  = ln >> 4;             // quad 0..3
    const int wm  = wv >> 2, wn = wv & 3;   // 2x4 wave grid; wave owns 128x64

    // staging geometry: thread tid covers elems e0..e0+7 of an 8192-elem tile
    const int e0 = tid * 8;
    const int r0 = e0 >> 5, c0 = e0 & 31;
    const bf16* gA0 = A  + (m0 + r0) * K + c0;          // rows   0..127
    const bf16* gA1 = A  + (m0 + 128 + r0) * K + c0;    // rows 128..255
    const bf16* gB0 = Bt + (n0 + r0) * K + c0;
    const bf16* gB1 = Bt + (n0 + 128 + r0) * K + c0;
    const int lw = wv * 512;             // wave-uniform LDS elem offset / half

    const int NT = K >> 5;               // K-tiles of 32

#define STAGE_A(bb, src) do { \
        gload_lds16(gA0 + (src) * 32, &As[bb][lw]); \
        gload_lds16(gA1 + (src) * 32, &As[bb][4096 + lw]); } while (0)
#define STAGE_B(bb, src) do { \
        gload_lds16(gB0 + (src) * 32, &Bs[bb][lw]); \
        gload_lds16(gB1 + (src) * 32, &Bs[bb][4096 + lw]); } while (0)

    // prologue: stage tiles 0,1,2 (12 issues; clamp keeps tiny-K safe)
    {
        const int s1 = 1 < NT ? 1 : 0;
        const int s2 = 2 < NT ? 2 : 0;
        STAGE_A(0, 0);  STAGE_B(0, 0);
        STAGE_A(1, s1); STAGE_B(1, s1);
        STAGE_A(2, s2); STAGE_B(2, s2);
    }

    f32x4 acc[8][4] = {};

    for (int kt = 0; kt < NT; ++kt) {
        const int b   = kt & 3;
        const int ks  = kt + 3;
        const int bb  = ks & 3;                  // target buffer (dead data)
        const int src = ks < NT ? ks : 0;        // dummy re-stage at the tail

        // counted wait: everything except the newest 8 issues (tiles kt+1,
        // kt+2) has landed -> tile kt's LDS is complete for THIS wave; the
        // raw barrier (no drain!) makes it complete for ALL waves.
        asm volatile("s_waitcnt vmcnt(8)" ::: "memory");
        __builtin_amdgcn_s_barrier();
        asm volatile("" ::: "memory");

        const bf16* Ab = As[b];
        const bf16* Bb = Bs[b];

        short8 af[4], bf[4];
        // phase 1: frags for upper 64 rows + all B, stage next A, MFMA 16
#pragma unroll
        for (int mi = 0; mi < 4; ++mi)
            af[mi] = *(const short8*)&Ab[(wm * 128 + mi * 16 + l15) * 32 + qd * 8];
#pragma unroll
        for (int ni = 0; ni < 4; ++ni)
            bf[ni] = *(const short8*)&Bb[(wn * 64 + ni * 16 + l15) * 32 + qd * 8];
        STAGE_A(bb, src);
        __builtin_amdgcn_s_setprio(1);
#pragma unroll
        for (int mi = 0; mi < 4; ++mi)
#pragma unroll
            for (int ni = 0; ni < 4; ++ni)
                acc[mi][ni] = __builtin_amdgcn_mfma_f32_16x16x32_bf16(
                    af[mi], bf[ni], acc[mi][ni], 0, 0, 0);
        __builtin_amdgcn_s_setprio(0);

        // phase 2: frags for lower 64 rows, stage next B, MFMA 16
#pragma unroll
        for (int mi = 0; mi < 4; ++mi)
            af[mi] = *(const short8*)&Ab[(wm * 128 + (mi + 4) * 16 + l15) * 32 + qd * 8];
        STAGE_B(bb, src);
        __builtin_amdgcn_s_setprio(1);
#pragma unroll
        for (int mi = 0; mi < 4; ++mi)
#pragma unroll
            for (int ni = 0; ni < 4; ++ni)
                acc[mi + 4][ni] = __builtin_amdgcn_mfma_f32_16x16x32_bf16(
                    af[mi], bf[ni], acc[mi + 4][ni], 0, 0, 0);
        __builtin_amdgcn_s_setprio(0);
    }
#undef STAGE_A
#undef STAGE_B

    // epilogue: C/D layout col=lane&15, row=quad*4+reg (verified mapping)
    const long ccol = n0 + wn * 64;
    float bsv[4];
#pragma unroll
    for (int ni = 0; ni < 4; ++ni)
        bsv[ni] = bias[ccol + ni * 16 + l15];
#pragma unroll
    for (int mi = 0; mi < 8; ++mi) {
#pragma unroll
        for (int r = 0; r < 4; ++r) {
            const long row = m0 + wm * 128 + mi * 16 + qd * 4 + r;
            OutT* cp = C + row * N + ccol + l15;
#pragma unroll
            for (int ni = 0; ni < 4; ++ni)
                store_out(cp + ni * 16, acc[mi][ni][r] + bsv[ni]);
        }
    }
}

// ---------------------------------------------------------------------------
// Blocked local attention on a CHUNK of tokens (bf16 in/out).
// qkv: (CH, 3072); out: (CH, 1024). blockIdx.x = 64-token block, .y = head.
// S = (Q*0.125) K^T -> softmax -> O = P V via 16x16x32 bf16 MFMA.
// ---------------------------------------------------------------------------
#define LROW 72   // padded LDS row (16B-aligned stride, breaks 128B bank period)

__global__ __launch_bounds__(256)
void attn_local(const bf16* __restrict__ qkv, bf16* __restrict__ out)
{
    __shared__ bf16 Qs[64 * LROW];
    __shared__ bf16 Ks[64 * LROW];
    __shared__ bf16 Vt[64 * LROW];   // transposed: Vt[d][m]
    __shared__ bf16 Ps[64 * LROW];

    const int cb = blockIdx.x;               // token block within chunk
    const int h  = blockIdx.y;               // head
    const int tid = threadIdx.x;

    const long qoff = (long)cb * 64 * 3072 + h * 64;   // q; +1024 = k, +2048 = v

    // load Q, K row-major; V transposed. 4096 elems each, 16 per thread.
#pragma unroll
    for (int p = 0; p < 2; ++p) {
        const int e = (p * 256 + tid) * 8;
        const int tk = e >> 6, cl = e & 63;
        const long g = qoff + (long)tk * 3072 + cl;
        *(uint4*)&Qs[tk * LROW + cl] = *(const uint4*)&qkv[g];
        *(uint4*)&Ks[tk * LROW + cl] = *(const uint4*)&qkv[g + 1024];
        uint4 vv = *(const uint4*)&qkv[g + 2048];
        const bf16* vp = (const bf16*)&vv;
#pragma unroll
        for (int j = 0; j < 8; ++j)
            Vt[(cl + j) * LROW + tk] = vp[j];
    }
    __syncthreads();

    const int wv = tid >> 6, ln = tid & 63, l15 = ln & 15, qd = ln >> 4;

    // S slab: wave wv handles query rows wv*16 .. wv*16+15
    f32x4 sacc[4] = {};
#pragma unroll
    for (int kk = 0; kk < 64; kk += 32) {
        short8 aq = *(const short8*)&Qs[(wv * 16 + l15) * LROW + kk + qd * 8];
#pragma unroll
        for (int ni = 0; ni < 4; ++ni) {
            short8 bk = *(const short8*)&Ks[(ni * 16 + l15) * LROW + kk + qd * 8];
            sacc[ni] = __builtin_amdgcn_mfma_f32_16x16x32_bf16(aq, bk, sacc[ni], 0, 0, 0);
        }
    }

    // softmax over 64 cols; row = wv*16 + qd*4 + r; cols = ni*16 + l15.
    // scale folded here: softmax(0.125 * S).
    float linv[4];
#pragma unroll
    for (int r = 0; r < 4; ++r) {
        float m = -3.4e38f;
#pragma unroll
        for (int ni = 0; ni < 4; ++ni) m = fmaxf(m, sacc[ni][r]);
#pragma unroll
        for (int off = 1; off < 16; off <<= 1) m = fmaxf(m, __shfl_xor(m, off));
        float s = 0.f, pv[4];
#pragma unroll
        for (int ni = 0; ni < 4; ++ni) {
            pv[ni] = __expf(0.125f * (sacc[ni][r] - m));
            s += pv[ni];
        }
#pragma unroll
        for (int off = 1; off < 16; off <<= 1) s += __shfl_xor(s, off);
        linv[r] = 1.f / s;
        const int row = wv * 16 + qd * 4 + r;
#pragma unroll
        for (int ni = 0; ni < 4; ++ni)
            Ps[row * LROW + ni * 16 + l15] = __float2bfloat16(pv[ni]);
    }
    __syncthreads();

    // O = P V: A-frag from Ps (A[m=l15][k]), B-frag from Vt (B[n=d][k=m])
    f32x4 oacc[4] = {};
#pragma unroll
    for (int kk = 0; kk < 64; kk += 32) {
        short8 ap = *(const short8*)&Ps[(wv * 16 + l15) * LROW + kk + qd * 8];
#pragma unroll
        for (int ni = 0; ni < 4; ++ni) {
            short8 bv = *(const short8*)&Vt[(ni * 16 + l15) * LROW + kk + qd * 8];
            oacc[ni] = __builtin_amdgcn_mfma_f32_16x16x32_bf16(ap, bv, oacc[ni], 0, 0, 0);
        }
    }

    const long obase = (long)cb * 64 * 1024 + h * 64;
#pragma unroll
    for (int r = 0; r < 4; ++r) {
        const int row = wv * 16 + qd * 4 + r;
#pragma unroll
        for (int ni = 0; ni < 4; ++ni)
            out[obase + (long)row * 1024 + ni * 16 + l15] =
                __float2bfloat16(oacc[ni][r] * linv[r]);
    }
}

// ---------------------------------------------------------------------------
extern "C" void kernel_launch(void* const* d_in, const int* in_sizes, int n_in,
                              void* d_out, int out_size, void* d_ws, size_t ws_size,
                              hipStream_t stream) {
    const float* x     = (const float*)d_in[0];   // (8, 4096, 1024) fp32
    const float* W_qkv = (const float*)d_in[1];   // (3072, 1024)    fp32
    const float* b_qkv = (const float*)d_in[2];   // (3072,)         fp32
    const float* W_out = (const float*)d_in[3];   // (1024, 1024)    fp32
    const float* b_out = (const float*)d_in[4];   // (1024,)         fp32
    float* out = (float*)d_out;                   // 32768 x 1024    fp32

    // Fixed bf16 slabs for weights: W_qkv 3072x1024, W_out 1024x1024.
    bf16* Wqkv_b = (bf16*)d_ws;                           // 6.29 MB
    bf16* Wout_b = Wqkv_b + (size_t)3072 * 1024;          // 2.10 MB
    bf16* chunk0 = Wout_b + (size_t)1024 * 1024;
    const size_t fixed_bytes = ((size_t)3072 * 1024 + (size_t)1024 * 1024) * 2;

    // Per-chunk slabs: xb CHx1024, qkvb CHx3072, attnb CHx1024 (bf16)
    // -> CH * 10240 bytes. CH must be a multiple of 256 (gemm256 tile).
    static const int cands[8] = {32768, 16384, 8192, 4096, 2048, 1024, 512, 256};
    int CH = 256;
    for (int i = 0; i < 8; ++i)
        if (fixed_bytes + (size_t)cands[i] * 10240 <= ws_size) { CH = cands[i]; break; }

    bf16* xb    = chunk0;                        // CH x 1024
    bf16* qkvb  = xb + (size_t)CH * 1024;        // CH x 3072
    bf16* attnb = qkvb + (size_t)CH * 3072;      // CH x 1024

    const dim3 blk(256);
    const dim3 gblk(512);

    // one-time weight conversion (cheap; done every call for graph safety)
    cvt_f32_bf16<<<dim3((3072 * 1024) / 2048), blk, 0, stream>>>(W_qkv, Wqkv_b, 3072 * 1024);
    cvt_f32_bf16<<<dim3((1024 * 1024) / 2048), blk, 0, stream>>>(W_out, Wout_b, 1024 * 1024);

    const int mt = CH / 256;                     // M-tiles per chunk

    for (int c0 = 0; c0 < 32768; c0 += CH) {
        const long ne = (long)CH * 1024;
        cvt_f32_bf16<<<dim3((int)(ne / 2048)), blk, 0, stream>>>(x + (size_t)c0 * 1024, xb, ne);
        // qkv = xb @ Wqkv^T + b_qkv   (M=CH, N=3072, K=1024), bf16 out
        gemm256<bf16><<<dim3(mt * (3072 / 256)), gblk, 0, stream>>>(
            xb, Wqkv_b, b_qkv, qkvb, 3072, 1024, 3072 / 256);
        // blocked local attention on the chunk
        attn_local<<<dim3(CH / 64, 16), blk, 0, stream>>>(qkvb, attnb);
        // out = attnb @ Wout^T + b_out (M=CH, N=1024, K=1024), fp32 out
        gemm256<float><<<dim3(mt * (1024 / 256)), gblk, 0, stream>>>(
            attnb, Wout_b, b_out, out + (size_t)c0 * 1024, 1024, 1024, 1024 / 256);
    }
}